// Round 1
// baseline (4879.308 us; speedup 1.0000x reference)
//
#include <hip/hip_runtime.h>

// Problem constants
#define BTOT 1024
#define TPTS 96
#define NV   7
#define HD   64
#define NC   3
#define NH   256   // ode hidden (4*H)
#define NB   4     // batch elements per block
#define ROWS (NB*NC)  // 12 (b,c) rows per block

// LDS layout (float offsets)
#define OFF_W1   0              // [66][256]        = 16896
#define OFF_W2   16896          // [64][260] (W2^T, padded) = 16640
#define OFF_HID  33536          // [12][256]        = 3072
#define OFF_HID2 36608          // [12][64]         = 768
#define OFF_YT   37376          // [12][64]         = 768
#define OFF_IE   38144          // [12]
#define OFF_TP   38156          // [96]
#define OFF_XM   38252          // [4][8]
#define OFF_H0   38284          // [4][64]          = 256
#define SMEM_FLOATS 38540
#define SMEM_BYTES  (SMEM_FLOATS * 4)

__device__ __forceinline__ float wave_sum64(float v) {
    v += __shfl_xor(v, 1);
    v += __shfl_xor(v, 2);
    v += __shfl_xor(v, 4);
    v += __shfl_xor(v, 8);
    v += __shfl_xor(v, 16);
    v += __shfl_xor(v, 32);
    return v;
}

__global__ __launch_bounds__(256, 1)
void node_fused(const float* __restrict__ x,
                const float* __restrict__ iw1, const float* __restrict__ ib1,
                const float* __restrict__ iw2, const float* __restrict__ ib2,
                const float* __restrict__ ow1, const float* __restrict__ ob1,
                const float* __restrict__ ow2, const float* __restrict__ ob2,
                const float* __restrict__ inter, const float* __restrict__ cons,
                const float* __restrict__ dw1, const float* __restrict__ db1,
                const float* __restrict__ dw2, const float* __restrict__ db2,
                const float* __restrict__ tpts,
                float* __restrict__ out)
{
    extern __shared__ float sm[];
    float* W1s  = sm + OFF_W1;
    float* W2s  = sm + OFF_W2;
    float* hids = sm + OFF_HID;
    float* hid2 = sm + OFF_HID2;
    float* yt   = sm + OFF_YT;
    float* ies  = sm + OFF_IE;
    float* tps  = sm + OFF_TP;
    float* xms  = sm + OFF_XM;
    float* h0s  = sm + OFF_H0;

    const int tid = threadIdx.x;
    const int g   = tid >> 6;   // wave id == local batch element (and decode component)
    const int ln  = tid & 63;   // lane
    const int b0  = blockIdx.x * NB;

    // ---------------- prologue: stage ODE weights into LDS ----------------
    #pragma unroll 1
    for (int i = 0; i < 66; ++i)
        W1s[i*NH + tid] = ow1[i*NH + tid];
    #pragma unroll 1
    for (int idx = tid; idx < NH*HD; idx += 256) {
        int hh = idx & 63, j = idx >> 6;     // ow2[j][hh], idx = j*64+hh
        W2s[hh*260 + j] = ow2[idx];          // transposed, padded row stride 260
    }
    if (tid < TPTS) tps[tid] = tpts[tid];

    // per-thread constants
    const float b1c  = ob1[tid];             // layer-1 bias for column tid
    const float w64  = ow1[64*NH + tid];     // W1 row 64 (interaction feature)
    const float w65  = ow1[65*NH + tid];     // W1 row 65 (time feature)
    const float b2c  = ob2[ln];              // layer-2 bias for output col ln
    const float db1r = (tid < 192) ? db1[tid] : 0.f;   // dec bias: c=g, k=ln

    // M = conservation @ interaction (3x3, per-thread regs)
    float M00,M01,M02,M10,M11,M12,M20,M21,M22;
    {
        float I0=inter[0],I1=inter[1],I2=inter[2],I3=inter[3],I4=inter[4];
        float I5=inter[5],I6=inter[6],I7=inter[7],I8=inter[8];
        float C0=cons[0],C1=cons[1],C2=cons[2],C3=cons[3],C4=cons[4];
        float C5=cons[5],C6=cons[6],C7=cons[7],C8=cons[8];
        M00=C0*I0+C1*I3+C2*I6; M01=C0*I1+C1*I4+C2*I7; M02=C0*I2+C1*I5+C2*I8;
        M10=C3*I0+C4*I3+C5*I6; M11=C3*I1+C4*I4+C5*I7; M12=C3*I2+C4*I5+C5*I8;
        M20=C6*I0+C7*I3+C8*I6; M21=C6*I1+C7*I4+C8*I7; M22=C6*I2+C7*I5+C8*I8;
    }

    // xmean over T for this block's 4 batch elements
    if (tid < NB*NV) {
        int bl = tid / NV, v = tid - NV*bl;
        const float* xp = x + ((size_t)(b0 + bl))*TPTS*NV + v;
        float s = 0.f;
        #pragma unroll 1
        for (int tt = 0; tt < TPTS; ++tt) s += xp[tt*NV];
        xms[bl*8 + v] = s * (1.f/(float)TPTS);
    }
    __syncthreads();

    // h0 = relu(xmean @ iw1 + ib1)  (wave g -> batch bl=g, lane -> col)
    {
        float a = ib1[ln];
        #pragma unroll
        for (int v = 0; v < NV; ++v) a = fmaf(xms[g*8 + v], iw1[v*HD + ln], a);
        h0s[g*HD + ln] = fmaxf(a, 0.f);
    }
    __syncthreads();

    // y0 = h0 @ iw2 + ib2  -> yt[12][64]
    if (tid < 192) {
        #pragma unroll 1
        for (int bl = 0; bl < NB; ++bl) {
            float a = ib2[tid];
            #pragma unroll 1
            for (int k = 0; k < HD; ++k)
                a = fmaf(h0s[bl*HD + k], iw2[k*192 + tid], a);
            yt[(bl*3 + (tid >> 6))*HD + (tid & 63)] = a;
        }
    }
    __syncthreads();

    // running state in registers: thread (g, ln) owns rows 3g+k, column ln
    float yb0 = yt[(3*g+0)*HD + ln];
    float yb1 = yt[(3*g+1)*HD + ln];
    float yb2 = yt[(3*g+2)*HD + ln];

    // per-row mean -> interaction effect -> ies[12]
    auto post_state = [&](float v0, float v1, float v2) {
        float s0 = wave_sum64(v0) * (1.f/64.f);
        float s1 = wave_sum64(v1) * (1.f/64.f);
        float s2 = wave_sum64(v2) * (1.f/64.f);
        float e0 = M00*s0 + M01*s1 + M02*s2;
        float e1 = M10*s0 + M11*s1 + M12*s2;
        float e2 = M20*s0 + M21*s1 + M22*s2;
        if (ln < 3) {
            float ev = (ln == 0) ? e0 : ((ln == 1) ? e1 : e2);
            ies[3*g + ln] = ev;
        }
    };

    // one ODE-func eval: reads yt/ies (valid after a barrier), returns d per row
    auto eval_f = [&](float ts, float& d0, float& d1, float& d2) {
        // ---- layer 1 (column-parallel: thread = hidden col tid) ----
        float acc[ROWS];
        #pragma unroll
        for (int r = 0; r < ROWS; ++r)
            acc[r] = fmaf(w64, ies[r], fmaf(w65, ts, b1c));
        const float4* y4 = (const float4*)yt;    // [12][16] float4
        #pragma unroll 2
        for (int i4 = 0; i4 < 16; ++i4) {
            float4 yv[ROWS];
            #pragma unroll
            for (int r = 0; r < ROWS; ++r) yv[r] = y4[r*16 + i4];
            #pragma unroll
            for (int ii = 0; ii < 4; ++ii) {
                float w = W1s[(i4*4 + ii)*NH + tid];
                #pragma unroll
                for (int r = 0; r < ROWS; ++r) {
                    float yx = (ii==0) ? yv[r].x : (ii==1) ? yv[r].y
                             : (ii==2) ? yv[r].z : yv[r].w;
                    acc[r] = fmaf(yx, w, acc[r]);
                }
            }
        }
        #pragma unroll
        for (int r = 0; r < ROWS; ++r) {
            float e = __expf(2.f * acc[r]);      // tanh = 1 - 2/(e^{2x}+1)
            hids[r*NH + tid] = 1.f - 2.f/(e + 1.f);
        }
        __syncthreads();
        // ---- layer 2 (wave g -> rows 3g+k, lane -> out col ln) ----
        float a0 = 0.f, a1 = 0.f, a2 = 0.f;
        const float4* w4 = (const float4*)(W2s + ln*260);
        const float4* p4 = (const float4*)(hids + (3*g+0)*NH);
        const float4* q4 = (const float4*)(hids + (3*g+1)*NH);
        const float4* r4 = (const float4*)(hids + (3*g+2)*NH);
        #pragma unroll 4
        for (int j4 = 0; j4 < 64; ++j4) {
            float4 w = w4[j4];
            float4 p = p4[j4];
            float4 q = q4[j4];
            float4 r = r4[j4];
            a0 = fmaf(p.w,w.w, fmaf(p.z,w.z, fmaf(p.y,w.y, fmaf(p.x,w.x, a0))));
            a1 = fmaf(q.w,w.w, fmaf(q.z,w.z, fmaf(q.y,w.y, fmaf(q.x,w.x, a1))));
            a2 = fmaf(r.w,w.w, fmaf(r.z,w.z, fmaf(r.y,w.y, fmaf(r.x,w.x, a2))));
        }
        d0 = a0 + b2c; d1 = a1 + b2c; d2 = a2 + b2c;
    };

    // fused decode for time index tix (yt holds y(tix); barrier already passed)
    auto decode_store = [&](int tix) {
        if (tid < 192) {   // c = g (waves 0..2), lane = dec hidden col
            float a0 = db1r, a1 = db1r, a2 = db1r, a3 = db1r;
            const float* d1p = dw1 + (size_t)g*HD*HD + ln;
            #pragma unroll 4
            for (int hh = 0; hh < HD; ++hh) {
                float w = d1p[hh*HD];
                a0 = fmaf(yt[(0*3 + g)*HD + hh], w, a0);
                a1 = fmaf(yt[(1*3 + g)*HD + hh], w, a1);
                a2 = fmaf(yt[(2*3 + g)*HD + hh], w, a2);
                a3 = fmaf(yt[(3*3 + g)*HD + hh], w, a3);
            }
            hid2[(0*3 + g)*HD + ln] = fmaxf(a0, 0.f);
            hid2[(1*3 + g)*HD + ln] = fmaxf(a1, 0.f);
            hid2[(2*3 + g)*HD + ln] = fmaxf(a2, 0.f);
            hid2[(3*3 + g)*HD + ln] = fmaxf(a3, 0.f);
        }
        __syncthreads();
        if (tid < 84) {    // 12 rows x 7 vars
            int r = tid / 7, v = tid - 7*r;
            int c = r % 3, bl = r / 3;
            float a = db2[c*NV + v];
            #pragma unroll 4
            for (int k = 0; k < HD; ++k)
                a = fmaf(hid2[r*HD + k], dw2[(c*HD + k)*NV + v], a);
            out[(((size_t)c*BTOT + (b0 + bl))*TPTS + tix)*NV + v] = a;
        }
        // no trailing barrier needed: next phase only reads yt/ies/W1s
    };

    post_state(yb0, yb1, yb2);
    __syncthreads();
    decode_store(0);

    float d0, d1, d2, ks0, ks1, ks2, yn0, yn1, yn2;
    #pragma unroll 1
    for (int s = 0; s < TPTS - 1; ++s) {
        const float t0 = tps[s], t1 = tps[s+1];
        const float dt = t1 - t0, hdt = 0.5f * dt;

        // stage 1: k1 = f(t0, y)
        eval_f(t0, d0, d1, d2);
        ks0 = d0; ks1 = d1; ks2 = d2;
        yn0 = fmaf(hdt, d0, yb0); yn1 = fmaf(hdt, d1, yb1); yn2 = fmaf(hdt, d2, yb2);
        yt[(3*g+0)*HD+ln] = yn0; yt[(3*g+1)*HD+ln] = yn1; yt[(3*g+2)*HD+ln] = yn2;
        post_state(yn0, yn1, yn2);
        __syncthreads();

        // stage 2: k2 = f(t0+h/2, y + h/2 k1)
        eval_f(t0 + hdt, d0, d1, d2);
        ks0 += 2.f*d0; ks1 += 2.f*d1; ks2 += 2.f*d2;
        yn0 = fmaf(hdt, d0, yb0); yn1 = fmaf(hdt, d1, yb1); yn2 = fmaf(hdt, d2, yb2);
        yt[(3*g+0)*HD+ln] = yn0; yt[(3*g+1)*HD+ln] = yn1; yt[(3*g+2)*HD+ln] = yn2;
        post_state(yn0, yn1, yn2);
        __syncthreads();

        // stage 3: k3 = f(t0+h/2, y + h/2 k2)
        eval_f(t0 + hdt, d0, d1, d2);
        ks0 += 2.f*d0; ks1 += 2.f*d1; ks2 += 2.f*d2;
        yn0 = fmaf(dt, d0, yb0); yn1 = fmaf(dt, d1, yb1); yn2 = fmaf(dt, d2, yb2);
        yt[(3*g+0)*HD+ln] = yn0; yt[(3*g+1)*HD+ln] = yn1; yt[(3*g+2)*HD+ln] = yn2;
        post_state(yn0, yn1, yn2);
        __syncthreads();

        // stage 4: k4 = f(t1, y + h k3);  y += h/6 (k1+2k2+2k3+k4)
        eval_f(t1, d0, d1, d2);
        ks0 += d0; ks1 += d1; ks2 += d2;
        const float c6 = dt * (1.f/6.f);
        yb0 = fmaf(c6, ks0, yb0); yb1 = fmaf(c6, ks1, yb1); yb2 = fmaf(c6, ks2, yb2);
        yt[(3*g+0)*HD+ln] = yb0; yt[(3*g+1)*HD+ln] = yb1; yt[(3*g+2)*HD+ln] = yb2;
        post_state(yb0, yb1, yb2);
        __syncthreads();

        decode_store(s + 1);
    }
}

extern "C" void kernel_launch(void* const* d_in, const int* in_sizes, int n_in,
                              void* d_out, int out_size, void* d_ws, size_t ws_size,
                              hipStream_t stream) {
    const float* x     = (const float*)d_in[0];
    const float* iw1   = (const float*)d_in[1];
    const float* ib1   = (const float*)d_in[2];
    const float* iw2   = (const float*)d_in[3];
    const float* ib2   = (const float*)d_in[4];
    const float* ow1   = (const float*)d_in[5];
    const float* ob1   = (const float*)d_in[6];
    const float* ow2   = (const float*)d_in[7];
    const float* ob2   = (const float*)d_in[8];
    const float* inter = (const float*)d_in[9];
    const float* cons  = (const float*)d_in[10];
    const float* dw1   = (const float*)d_in[11];
    const float* db1   = (const float*)d_in[12];
    const float* dw2   = (const float*)d_in[13];
    const float* db2   = (const float*)d_in[14];
    const float* tpts  = (const float*)d_in[15];
    float* out = (float*)d_out;

    // allow >64KB dynamic LDS (idempotent, host-side, graph-capture safe)
    (void)hipFuncSetAttribute((const void*)node_fused,
                              hipFuncAttributeMaxDynamicSharedMemorySize,
                              SMEM_BYTES);

    node_fused<<<BTOT / NB, 256, SMEM_BYTES, stream>>>(
        x, iw1, ib1, iw2, ib2, ow1, ob1, ow2, ob2,
        inter, cons, dw1, db1, dw2, db2, tpts, out);
}